// Round 3
// baseline (200.641 us; speedup 1.0000x reference)
//
#include <hip/hip_runtime.h>

// LoopHead: node MLP (32->64->32) then edge decoder (gather/concat -> 64 -> 1)
// Wire dtypes per the reference: ALL float tensors fp32, edge_index int32,
// output fp32. MFMA via the version-stable v4i16-signature builtin
// __builtin_amdgcn_mfma_f32_16x16x16bf16_1k (K=16). No HIP vector classes,
// no unions, no __bf16 — only plain ext_vector typedefs.

typedef short bfrag4 __attribute__((ext_vector_type(4)));  // 4 bf16 (A/B frag)
typedef float f32x4v __attribute__((ext_vector_type(4)));  // fp32 x4

#define N_NODES 100000
#define N_EDGES 3200000

__device__ __forceinline__ unsigned short f2bf(float f) {
    union_free_cast: ;
    unsigned int i = __float_as_uint(f);
    unsigned int r = i + 0x7FFFu + ((i >> 16) & 1u);  // RNE
    return (unsigned short)(r >> 16);
}

__device__ __forceinline__ bfrag4 cvt4(float x0, float x1, float x2, float x3) {
    bfrag4 v;
    v[0] = (short)f2bf(x0);
    v[1] = (short)f2bf(x1);
    v[2] = (short)f2bf(x2);
    v[3] = (short)f2bf(x3);
    return v;
}

// ---------------- Kernel 1: node projection -> z_loop (bf16 [N,32]) --------
__global__ __launch_bounds__(256) void node_proj_kernel(
    const float* __restrict__ z_mod,   // [N,32] fp32
    const float* __restrict__ w1,      // [32,64] row-major (k,n)
    const float* __restrict__ b1,      // [64]
    const float* __restrict__ w2,      // [64,32] row-major (k,n)
    const float* __restrict__ b2,      // [32]
    unsigned short* __restrict__ z_loop)  // [N,32] bf16 out (workspace)
{
    // per-wave LDS region for the h (C-layout -> A-layout) round trip.
    // row stride 72 ushorts breaks the power-of-2 read conflict.
    __shared__ unsigned short hbuf[4][16 * 72];

    const int tid  = threadIdx.x;
    const int wave = tid >> 6;
    const int lane = tid & 63;
    const int quad = lane >> 4;
    const int col  = lane & 15;

    // B-frags (k = step*16 + quad*4 + j, n = col + 16*t), converted fp32->bf16
    bfrag4 bw1[2][4];   // stage 1: K=32 (2 steps), N=64 (4 n-tiles)
    float  bias1[4];
    for (int t = 0; t < 4; ++t) {
        const int n = col + 16 * t;
        for (int s = 0; s < 2; ++s)
            for (int j = 0; j < 4; ++j)
                bw1[s][t][j] = (short)f2bf(w1[(s * 16 + quad * 4 + j) * 64 + n]);
        bias1[t] = b1[n];
    }
    bfrag4 bw2[4][2];   // stage 2: K=64 (4 steps), N=32 (2 n-tiles)
    float  bias2[2];
    for (int t = 0; t < 2; ++t) {
        const int n = col + 16 * t;
        for (int s = 0; s < 4; ++s)
            for (int j = 0; j < 4; ++j)
                bw2[s][t][j] = (short)f2bf(w2[(s * 16 + quad * 4 + j) * 32 + n]);
        bias2[t] = b2[n];
    }

    unsigned short* hrow = &hbuf[wave][0];

    const int gwave  = blockIdx.x * 4 + wave;
    const int nwaves = gridDim.x * 4;
    const int ntiles = N_NODES / 16;   // 6250, exact

    for (int tile = gwave; tile < ntiles; tile += nwaves) {
        const int node0 = tile * 16;
        const float* zrow = z_mod + (size_t)(node0 + col) * 32;

        // stage 1: A-frags from global fp32 (A[m=col][k = s*16 + quad*4 + j])
        f32x4v za0 = *(const f32x4v*)(zrow + 0 * 16 + quad * 4);
        f32x4v za1 = *(const f32x4v*)(zrow + 1 * 16 + quad * 4);
        bfrag4 a10 = cvt4(za0[0], za0[1], za0[2], za0[3]);
        bfrag4 a11 = cvt4(za1[0], za1[1], za1[2], za1[3]);

        f32x4v acc[4];
        for (int t = 0; t < 4; ++t) {
            f32x4v c = {bias1[t], bias1[t], bias1[t], bias1[t]};
            c = __builtin_amdgcn_mfma_f32_16x16x16bf16_1k(a10, bw1[0][t], c, 0, 0, 0);
            c = __builtin_amdgcn_mfma_f32_16x16x16bf16_1k(a11, bw1[1][t], c, 0, 0, 0);
            acc[t] = c;
        }

        // relu -> LDS as bf16 (C-layout: lane holds h[quad*4+r][col+16t])
        for (int t = 0; t < 4; ++t)
            for (int r = 0; r < 4; ++r) {
                float v = acc[t][r];
                v = v > 0.f ? v : 0.f;
                hrow[(quad * 4 + r) * 72 + (col + 16 * t)] = f2bf(v);
            }
        asm volatile("" ::: "memory");   // same-wave DS ops are in-order

        // stage 2: read h back in A-layout (8B frags, 8B-aligned: 72*2=144B)
        f32x4v acc2[2];
        for (int t = 0; t < 2; ++t)
            acc2[t] = (f32x4v){bias2[t], bias2[t], bias2[t], bias2[t]};
        for (int s = 0; s < 4; ++s) {
            bfrag4 a2 = *(const bfrag4*)(hrow + col * 72 + s * 16 + quad * 4);
            for (int t = 0; t < 2; ++t)
                acc2[t] = __builtin_amdgcn_mfma_f32_16x16x16bf16_1k(a2, bw2[s][t], acc2[t], 0, 0, 0);
        }
        asm volatile("" ::: "memory");

        // store z_loop bf16 (C-layout: row = quad*4+r, col = n)
        for (int t = 0; t < 2; ++t)
            for (int r = 0; r < 4; ++r)
                z_loop[(size_t)(node0 + quad * 4 + r) * 32 + (col + 16 * t)] =
                    f2bf(acc2[t][r]);
    }
}

// ---------------- Kernel 2: edge decoder ------------------------------------
__global__ __launch_bounds__(256) void edge_dec_kernel(
    const int*            __restrict__ eidx,     // [2, E] int32
    const unsigned short* __restrict__ z_loop,   // [N,32] bf16
    const float*          __restrict__ dw1,      // [64,64] row-major (k,n)
    const float*          __restrict__ db1,      // [64]
    const float*          __restrict__ dw2,      // [64]
    const float*          __restrict__ db2,      // [1]
    float* __restrict__ out)                     // [E] fp32
{
    const int tid  = threadIdx.x;
    const int wave = tid >> 6;
    const int lane = tid & 63;
    const int quad = lane >> 4;
    const int col  = lane & 15;
    (void)wave;

    // dw1 B-frags: 4 K-steps x 4 n-tiles
    bfrag4 bw[4][4];
    float  bias1[4], w2v[4];
    for (int t = 0; t < 4; ++t) {
        const int n = col + 16 * t;
        for (int s = 0; s < 4; ++s)
            for (int j = 0; j < 4; ++j)
                bw[s][t][j] = (short)f2bf(dw1[(s * 16 + quad * 4 + j) * 64 + n]);
        bias1[t] = db1[n];
        w2v[t]   = dw2[n];
    }
    const float bias2 = db2[0];

    const int gwave  = blockIdx.x * 4 + (tid >> 6);
    const int nwaves = gridDim.x * 4;
    const int ntiles = N_EDGES / 16;   // 200000, exact

    for (int tile = gwave; tile < ntiles; tile += nwaves) {
        const int e0 = tile * 16;
        const int src = eidx[e0 + col];
        const int dst = eidx[N_EDGES + e0 + col];
        const unsigned short* zi = z_loop + (size_t)src * 32;
        const unsigned short* zj = z_loop + (size_t)dst * 32;

        // gathered 8B loads ARE the A-frags: zi -> k 0..31, zj -> k 32..63
        bfrag4 a0 = *(const bfrag4*)(zi + 0 * 16 + quad * 4);
        bfrag4 a1 = *(const bfrag4*)(zi + 1 * 16 + quad * 4);
        bfrag4 a2 = *(const bfrag4*)(zj + 0 * 16 + quad * 4);
        bfrag4 a3 = *(const bfrag4*)(zj + 1 * 16 + quad * 4);

        f32x4v acc[4];
        for (int t = 0; t < 4; ++t) {
            f32x4v c = {bias1[t], bias1[t], bias1[t], bias1[t]};
            c = __builtin_amdgcn_mfma_f32_16x16x16bf16_1k(a0, bw[0][t], c, 0, 0, 0);
            c = __builtin_amdgcn_mfma_f32_16x16x16bf16_1k(a1, bw[1][t], c, 0, 0, 0);
            c = __builtin_amdgcn_mfma_f32_16x16x16bf16_1k(a2, bw[2][t], c, 0, 0, 0);
            c = __builtin_amdgcn_mfma_f32_16x16x16bf16_1k(a3, bw[3][t], c, 0, 0, 0);
            acc[t] = c;
        }

        // relu + fp32 dot with dw2 (per-lane partial over 4 of 64 columns)
        float p0 = 0.f, p1 = 0.f, p2 = 0.f, p3 = 0.f;
        for (int t = 0; t < 4; ++t) {
            float v0 = acc[t][0]; v0 = v0 > 0.f ? v0 : 0.f;
            float v1 = acc[t][1]; v1 = v1 > 0.f ? v1 : 0.f;
            float v2 = acc[t][2]; v2 = v2 > 0.f ? v2 : 0.f;
            float v3 = acc[t][3]; v3 = v3 > 0.f ? v3 : 0.f;
            p0 += v0 * w2v[t];
            p1 += v1 * w2v[t];
            p2 += v2 * w2v[t];
            p3 += v3 * w2v[t];
        }
        // butterfly across the 16-lane column group (masks <16 stay in-group)
        for (int msk = 1; msk <= 8; msk <<= 1) {
            p0 += __shfl_xor(p0, msk, 64);
            p1 += __shfl_xor(p1, msk, 64);
            p2 += __shfl_xor(p2, msk, 64);
            p3 += __shfl_xor(p3, msk, 64);
        }

        if (col == 0) {
            f32x4v ov = {p0 + bias2, p1 + bias2, p2 + bias2, p3 + bias2};
            *(f32x4v*)(out + e0 + quad * 4) = ov;   // 16B aligned: e0 % 16 == 0
        }
    }
}

extern "C" void kernel_launch(void* const* d_in, const int* in_sizes, int n_in,
                              void* d_out, int out_size, void* d_ws, size_t ws_size,
                              hipStream_t stream) {
    const float* z_mod = (const float*)d_in[0];
    const int*   eidx  = (const int*)d_in[1];
    const float* w1    = (const float*)d_in[2];
    const float* b1    = (const float*)d_in[3];
    const float* w2    = (const float*)d_in[4];
    const float* b2    = (const float*)d_in[5];
    const float* dw1   = (const float*)d_in[6];
    const float* db1   = (const float*)d_in[7];
    const float* dw2   = (const float*)d_in[8];
    const float* db2   = (const float*)d_in[9];
    float*          out    = (float*)d_out;
    unsigned short* z_loop = (unsigned short*)d_ws;   // 100000*32*2B = 6.4 MB

    node_proj_kernel<<<512, 256, 0, stream>>>(z_mod, w1, b1, w2, b2, z_loop);
    edge_dec_kernel<<<1536, 256, 0, stream>>>(eidx, z_loop, dw1, db1, dw2, db2, out);
}

// Round 6
// 166.020 us; speedup vs baseline: 1.2085x; 1.2085x over previous
//
#include <hip/hip_runtime.h>

// LoopHead: node MLP (32->64->32) then edge decoder (gather/concat -> 64 -> 1)
// Wire dtypes per the reference: fp32 tensors, int32 edge_index, fp32 out.
// Base = round-3 kernel (fully passed incl. post-timing checks).
// Delta (edge kernel only): x32 MFMA (16B gathers = A-frags) + 2-tile unroll
// for memory-level parallelism. No software pipeline, no clamps.

typedef short bfrag4 __attribute__((ext_vector_type(4)));  // 4 bf16 (x16 frag)
typedef short s16x8  __attribute__((ext_vector_type(8)));  // 8 bf16 (x32 frag)
typedef float f32x4v __attribute__((ext_vector_type(4)));  // fp32 x4

#define N_NODES 100000
#define N_EDGES 3200000

__device__ __forceinline__ unsigned short f2bf(float f) {
    unsigned int i = __float_as_uint(f);
    unsigned int r = i + 0x7FFFu + ((i >> 16) & 1u);  // RNE
    return (unsigned short)(r >> 16);
}

__device__ __forceinline__ bfrag4 cvt4(float x0, float x1, float x2, float x3) {
    bfrag4 v;
    v[0] = (short)f2bf(x0);
    v[1] = (short)f2bf(x1);
    v[2] = (short)f2bf(x2);
    v[3] = (short)f2bf(x3);
    return v;
}

// ---------------- Kernel 1: node projection -> z_loop (bf16 [N,32]) --------
// (verbatim round-3 version — proven through all harness checks)
__global__ __launch_bounds__(256) void node_proj_kernel(
    const float* __restrict__ z_mod,   // [N,32] fp32
    const float* __restrict__ w1,      // [32,64] row-major (k,n)
    const float* __restrict__ b1,      // [64]
    const float* __restrict__ w2,      // [64,32] row-major (k,n)
    const float* __restrict__ b2,      // [32]
    unsigned short* __restrict__ z_loop)  // [N,32] bf16 out (workspace)
{
    __shared__ unsigned short hbuf[4][16 * 72];

    const int tid  = threadIdx.x;
    const int wave = tid >> 6;
    const int lane = tid & 63;
    const int quad = lane >> 4;
    const int col  = lane & 15;

    bfrag4 bw1[2][4];   // stage 1: K=32 (2 steps), N=64 (4 n-tiles)
    float  bias1[4];
    for (int t = 0; t < 4; ++t) {
        const int n = col + 16 * t;
        for (int s = 0; s < 2; ++s)
            for (int j = 0; j < 4; ++j)
                bw1[s][t][j] = (short)f2bf(w1[(s * 16 + quad * 4 + j) * 64 + n]);
        bias1[t] = b1[n];
    }
    bfrag4 bw2[4][2];   // stage 2: K=64 (4 steps), N=32 (2 n-tiles)
    float  bias2[2];
    for (int t = 0; t < 2; ++t) {
        const int n = col + 16 * t;
        for (int s = 0; s < 4; ++s)
            for (int j = 0; j < 4; ++j)
                bw2[s][t][j] = (short)f2bf(w2[(s * 16 + quad * 4 + j) * 32 + n]);
        bias2[t] = b2[n];
    }

    unsigned short* hrow = &hbuf[wave][0];

    const int gwave  = blockIdx.x * 4 + wave;
    const int nwaves = gridDim.x * 4;
    const int ntiles = N_NODES / 16;   // 6250, exact

    for (int tile = gwave; tile < ntiles; tile += nwaves) {
        const int node0 = tile * 16;
        const float* zrow = z_mod + (size_t)(node0 + col) * 32;

        f32x4v za0 = *(const f32x4v*)(zrow + 0 * 16 + quad * 4);
        f32x4v za1 = *(const f32x4v*)(zrow + 1 * 16 + quad * 4);
        bfrag4 a10 = cvt4(za0[0], za0[1], za0[2], za0[3]);
        bfrag4 a11 = cvt4(za1[0], za1[1], za1[2], za1[3]);

        f32x4v acc[4];
        for (int t = 0; t < 4; ++t) {
            f32x4v c = {bias1[t], bias1[t], bias1[t], bias1[t]};
            c = __builtin_amdgcn_mfma_f32_16x16x16bf16_1k(a10, bw1[0][t], c, 0, 0, 0);
            c = __builtin_amdgcn_mfma_f32_16x16x16bf16_1k(a11, bw1[1][t], c, 0, 0, 0);
            acc[t] = c;
        }

        for (int t = 0; t < 4; ++t)
            for (int r = 0; r < 4; ++r) {
                float v = acc[t][r];
                v = v > 0.f ? v : 0.f;
                hrow[(quad * 4 + r) * 72 + (col + 16 * t)] = f2bf(v);
            }
        asm volatile("" ::: "memory");

        f32x4v acc2[2];
        for (int t = 0; t < 2; ++t)
            acc2[t] = (f32x4v){bias2[t], bias2[t], bias2[t], bias2[t]};
        for (int s = 0; s < 4; ++s) {
            bfrag4 a2 = *(const bfrag4*)(hrow + col * 72 + s * 16 + quad * 4);
            for (int t = 0; t < 2; ++t)
                acc2[t] = __builtin_amdgcn_mfma_f32_16x16x16bf16_1k(a2, bw2[s][t], acc2[t], 0, 0, 0);
        }
        asm volatile("" ::: "memory");

        for (int t = 0; t < 2; ++t)
            for (int r = 0; r < 4; ++r)
                z_loop[(size_t)(node0 + quad * 4 + r) * 32 + (col + 16 * t)] =
                    f2bf(acc2[t][r]);
    }
}

// ---------------- Kernel 2: edge decoder (x32 MFMA, 2-tile unroll) ----------
__global__ __launch_bounds__(256) void edge_dec_kernel(
    const int*            __restrict__ eidx,     // [2, E] int32
    const unsigned short* __restrict__ z_loop,   // [N,32] bf16
    const float*          __restrict__ dw1,      // [64,64] row-major (k,n)
    const float*          __restrict__ db1,      // [64]
    const float*          __restrict__ dw2,      // [64]
    const float*          __restrict__ db2,      // [1]
    float* __restrict__ out)                     // [E] fp32
{
    const int tid  = threadIdx.x;
    const int lane = tid & 63;
    const int quad = lane >> 4;
    const int col  = lane & 15;

    // dw1 B-frags for x32 MFMA: B[k = s*32 + quad*8 + j][n = col + 16t]
    s16x8 bw[2][4];
    float bias1[4], w2v[4];
    for (int t = 0; t < 4; ++t) {
        const int n = col + 16 * t;
        for (int s = 0; s < 2; ++s)
            for (int j = 0; j < 8; ++j)
                bw[s][t][j] = (short)f2bf(dw1[(s * 32 + quad * 8 + j) * 64 + n]);
        bias1[t] = db1[n];
        w2v[t]   = dw2[n];
    }
    const float bias2 = db2[0];

    const int gwave  = blockIdx.x * 4 + (tid >> 6);
    const int nwaves = gridDim.x * 4;
    const int npairs = N_EDGES / 32;   // 100000, exact (2 tiles of 16 per iter)

    for (int p = gwave; p < npairs; p += nwaves) {
        const int e0 = p * 32;

        // all index loads up front (independent -> 4 outstanding dword loads)
        const int srcA = eidx[e0 + col];
        const int srcB = eidx[e0 + 16 + col];
        const int dstA = eidx[N_EDGES + e0 + col];
        const int dstB = eidx[N_EDGES + e0 + 16 + col];

        // 4 independent 16B gathers — each IS an A-fragment
        // (A[m=lane&15][k=quad*8+j]); B's loads overlap A's compute.
        s16x8 aA0 = *(const s16x8*)(z_loop + (size_t)srcA * 32 + quad * 8);
        s16x8 aA1 = *(const s16x8*)(z_loop + (size_t)dstA * 32 + quad * 8);
        s16x8 aB0 = *(const s16x8*)(z_loop + (size_t)srcB * 32 + quad * 8);
        s16x8 aB1 = *(const s16x8*)(z_loop + (size_t)dstB * 32 + quad * 8);

        f32x4v accA[4], accB[4];
        for (int t = 0; t < 4; ++t) {
            f32x4v c = {bias1[t], bias1[t], bias1[t], bias1[t]};
            c = __builtin_amdgcn_mfma_f32_16x16x32_bf16(aA0, bw[0][t], c, 0, 0, 0);
            c = __builtin_amdgcn_mfma_f32_16x16x32_bf16(aA1, bw[1][t], c, 0, 0, 0);
            accA[t] = c;
        }
        for (int t = 0; t < 4; ++t) {
            f32x4v c = {bias1[t], bias1[t], bias1[t], bias1[t]};
            c = __builtin_amdgcn_mfma_f32_16x16x32_bf16(aB0, bw[0][t], c, 0, 0, 0);
            c = __builtin_amdgcn_mfma_f32_16x16x32_bf16(aB1, bw[1][t], c, 0, 0, 0);
            accB[t] = c;
        }

        // relu + fp32 dot with dw2 (per-lane partials over 4 of 64 units)
        float pA0 = 0.f, pA1 = 0.f, pA2 = 0.f, pA3 = 0.f;
        float pB0 = 0.f, pB1 = 0.f, pB2 = 0.f, pB3 = 0.f;
        for (int t = 0; t < 4; ++t) {
            float v;
            v = accA[t][0]; v = v > 0.f ? v : 0.f; pA0 += v * w2v[t];
            v = accA[t][1]; v = v > 0.f ? v : 0.f; pA1 += v * w2v[t];
            v = accA[t][2]; v = v > 0.f ? v : 0.f; pA2 += v * w2v[t];
            v = accA[t][3]; v = v > 0.f ? v : 0.f; pA3 += v * w2v[t];
            v = accB[t][0]; v = v > 0.f ? v : 0.f; pB0 += v * w2v[t];
            v = accB[t][1]; v = v > 0.f ? v : 0.f; pB1 += v * w2v[t];
            v = accB[t][2]; v = v > 0.f ? v : 0.f; pB2 += v * w2v[t];
            v = accB[t][3]; v = v > 0.f ? v : 0.f; pB3 += v * w2v[t];
        }
        // butterfly across the 16-lane column group
        for (int msk = 1; msk <= 8; msk <<= 1) {
            pA0 += __shfl_xor(pA0, msk, 64);
            pA1 += __shfl_xor(pA1, msk, 64);
            pA2 += __shfl_xor(pA2, msk, 64);
            pA3 += __shfl_xor(pA3, msk, 64);
            pB0 += __shfl_xor(pB0, msk, 64);
            pB1 += __shfl_xor(pB1, msk, 64);
            pB2 += __shfl_xor(pB2, msk, 64);
            pB3 += __shfl_xor(pB3, msk, 64);
        }

        if (col == 0) {
            f32x4v ovA = {pA0 + bias2, pA1 + bias2, pA2 + bias2, pA3 + bias2};
            f32x4v ovB = {pB0 + bias2, pB1 + bias2, pB2 + bias2, pB3 + bias2};
            *(f32x4v*)(out + e0 + quad * 4)      = ovA;   // 16B aligned
            *(f32x4v*)(out + e0 + 16 + quad * 4) = ovB;
        }
    }
}

extern "C" void kernel_launch(void* const* d_in, const int* in_sizes, int n_in,
                              void* d_out, int out_size, void* d_ws, size_t ws_size,
                              hipStream_t stream) {
    const float* z_mod = (const float*)d_in[0];
    const int*   eidx  = (const int*)d_in[1];
    const float* w1    = (const float*)d_in[2];
    const float* b1    = (const float*)d_in[3];
    const float* w2    = (const float*)d_in[4];
    const float* b2    = (const float*)d_in[5];
    const float* dw1   = (const float*)d_in[6];
    const float* db1   = (const float*)d_in[7];
    const float* dw2   = (const float*)d_in[8];
    const float* db2   = (const float*)d_in[9];
    float*          out    = (float*)d_out;
    unsigned short* z_loop = (unsigned short*)d_ws;   // 100000*32*2B = 6.4 MB

    node_proj_kernel<<<512, 256, 0, stream>>>(z_mod, w1, b1, w2, b2, z_loop);
    edge_dec_kernel<<<1536, 256, 0, stream>>>(eidx, z_loop, dw1, db1, dw2, db2, out);
}

// Round 7
// 161.060 us; speedup vs baseline: 1.2458x; 1.0308x over previous
//
#include <hip/hip_runtime.h>

// LoopHead: node MLP (32->64->32) then edge decoder (gather/concat -> 64 -> 1)
// Wire dtypes per the reference: fp32 tensors, int32 edge_index, fp32 out.
// R7 delta (edge kernel only): transposed GEMM — weights are the A-operand
// (m=hidden), gathered features are the B-operand (n=edge). Same 16B gathers
// (A- and B-frag index math is identical), same MFMA count, but the dw2-dot
// reduce shrinks from 4 butterfly steps x 8 partials to 2 steps x 1 partial,
// and the output store becomes one coalesced 128B store by lanes 0-31.

typedef short bfrag4 __attribute__((ext_vector_type(4)));  // 4 bf16 (x16 frag)
typedef short s16x8  __attribute__((ext_vector_type(8)));  // 8 bf16 (x32 frag)
typedef float f32x4v __attribute__((ext_vector_type(4)));  // fp32 x4

#define N_NODES 100000
#define N_EDGES 3200000

__device__ __forceinline__ unsigned short f2bf(float f) {
    unsigned int i = __float_as_uint(f);
    unsigned int r = i + 0x7FFFu + ((i >> 16) & 1u);  // RNE
    return (unsigned short)(r >> 16);
}

__device__ __forceinline__ bfrag4 cvt4(float x0, float x1, float x2, float x3) {
    bfrag4 v;
    v[0] = (short)f2bf(x0);
    v[1] = (short)f2bf(x1);
    v[2] = (short)f2bf(x2);
    v[3] = (short)f2bf(x3);
    return v;
}

// ---------------- Kernel 1: node projection -> z_loop (bf16 [N,32]) --------
// (verbatim round-3/6 version — proven through all harness checks)
__global__ __launch_bounds__(256) void node_proj_kernel(
    const float* __restrict__ z_mod,   // [N,32] fp32
    const float* __restrict__ w1,      // [32,64] row-major (k,n)
    const float* __restrict__ b1,      // [64]
    const float* __restrict__ w2,      // [64,32] row-major (k,n)
    const float* __restrict__ b2,      // [32]
    unsigned short* __restrict__ z_loop)  // [N,32] bf16 out (workspace)
{
    __shared__ unsigned short hbuf[4][16 * 72];

    const int tid  = threadIdx.x;
    const int wave = tid >> 6;
    const int lane = tid & 63;
    const int quad = lane >> 4;
    const int col  = lane & 15;

    bfrag4 bw1[2][4];   // stage 1: K=32 (2 steps), N=64 (4 n-tiles)
    float  bias1[4];
    for (int t = 0; t < 4; ++t) {
        const int n = col + 16 * t;
        for (int s = 0; s < 2; ++s)
            for (int j = 0; j < 4; ++j)
                bw1[s][t][j] = (short)f2bf(w1[(s * 16 + quad * 4 + j) * 64 + n]);
        bias1[t] = b1[n];
    }
    bfrag4 bw2[4][2];   // stage 2: K=64 (4 steps), N=32 (2 n-tiles)
    float  bias2[2];
    for (int t = 0; t < 2; ++t) {
        const int n = col + 16 * t;
        for (int s = 0; s < 4; ++s)
            for (int j = 0; j < 4; ++j)
                bw2[s][t][j] = (short)f2bf(w2[(s * 16 + quad * 4 + j) * 32 + n]);
        bias2[t] = b2[n];
    }

    unsigned short* hrow = &hbuf[wave][0];

    const int gwave  = blockIdx.x * 4 + wave;
    const int nwaves = gridDim.x * 4;
    const int ntiles = N_NODES / 16;   // 6250, exact

    for (int tile = gwave; tile < ntiles; tile += nwaves) {
        const int node0 = tile * 16;
        const float* zrow = z_mod + (size_t)(node0 + col) * 32;

        f32x4v za0 = *(const f32x4v*)(zrow + 0 * 16 + quad * 4);
        f32x4v za1 = *(const f32x4v*)(zrow + 1 * 16 + quad * 4);
        bfrag4 a10 = cvt4(za0[0], za0[1], za0[2], za0[3]);
        bfrag4 a11 = cvt4(za1[0], za1[1], za1[2], za1[3]);

        f32x4v acc[4];
        for (int t = 0; t < 4; ++t) {
            f32x4v c = {bias1[t], bias1[t], bias1[t], bias1[t]};
            c = __builtin_amdgcn_mfma_f32_16x16x16bf16_1k(a10, bw1[0][t], c, 0, 0, 0);
            c = __builtin_amdgcn_mfma_f32_16x16x16bf16_1k(a11, bw1[1][t], c, 0, 0, 0);
            acc[t] = c;
        }

        for (int t = 0; t < 4; ++t)
            for (int r = 0; r < 4; ++r) {
                float v = acc[t][r];
                v = v > 0.f ? v : 0.f;
                hrow[(quad * 4 + r) * 72 + (col + 16 * t)] = f2bf(v);
            }
        asm volatile("" ::: "memory");

        f32x4v acc2[2];
        for (int t = 0; t < 2; ++t)
            acc2[t] = (f32x4v){bias2[t], bias2[t], bias2[t], bias2[t]};
        for (int s = 0; s < 4; ++s) {
            bfrag4 a2 = *(const bfrag4*)(hrow + col * 72 + s * 16 + quad * 4);
            for (int t = 0; t < 2; ++t)
                acc2[t] = __builtin_amdgcn_mfma_f32_16x16x16bf16_1k(a2, bw2[s][t], acc2[t], 0, 0, 0);
        }
        asm volatile("" ::: "memory");

        for (int t = 0; t < 2; ++t)
            for (int r = 0; r < 4; ++r)
                z_loop[(size_t)(node0 + quad * 4 + r) * 32 + (col + 16 * t)] =
                    f2bf(acc2[t][r]);
    }
}

// ---------------- Kernel 2: edge decoder (transposed GEMM, 2-tile unroll) ---
__global__ __launch_bounds__(256) void edge_dec_kernel(
    const int*            __restrict__ eidx,     // [2, E] int32
    const unsigned short* __restrict__ z_loop,   // [N,32] bf16
    const float*          __restrict__ dw1,      // [64,64] row-major (k,n)
    const float*          __restrict__ db1,      // [64]
    const float*          __restrict__ dw2,      // [64]
    const float*          __restrict__ db2,      // [1]
    float* __restrict__ out)                     // [E] fp32
{
    const int tid  = threadIdx.x;
    const int lane = tid & 63;
    const int quad = lane >> 4;
    const int col  = lane & 15;

    // A-frags = dw1^T tiles: aw[s][mt] holds A[m = 16mt+col][k = 32s+quad*8+j]
    //   = dw1[k][h]  (h = 16mt+col)
    s16x8 aw[2][4];
    float bias1[4][4];   // [mt][r] = db1[16mt + quad*4 + r]  (C-row bias)
    float w2v[4][4];     // [mt][r] = dw2[16mt + quad*4 + r]
    for (int mt = 0; mt < 4; ++mt) {
        const int h = 16 * mt + col;
        for (int s = 0; s < 2; ++s)
            for (int j = 0; j < 8; ++j)
                aw[s][mt][j] = (short)f2bf(dw1[(32 * s + quad * 8 + j) * 64 + h]);
        for (int r = 0; r < 4; ++r) {
            bias1[mt][r] = db1[16 * mt + quad * 4 + r];
            w2v[mt][r]   = dw2[16 * mt + quad * 4 + r];
        }
    }
    const float bias2 = db2[0];

    const int gwave  = blockIdx.x * 4 + (tid >> 6);
    const int nwaves = gridDim.x * 4;
    const int npairs = N_EDGES / 32;   // 100000, exact (2 tiles of 16 per iter)

    for (int p = gwave; p < npairs; p += nwaves) {
        const int e0 = p * 32;

        // index loads up front (4 independent dword loads)
        const int srcA = eidx[e0 + col];
        const int srcB = eidx[e0 + 16 + col];
        const int dstA = eidx[N_EDGES + e0 + col];
        const int dstB = eidx[N_EDGES + e0 + 16 + col];

        // 4 independent 16B gathers — each IS a B-fragment:
        // B[k=quad*8+j][n=col] = x[e0+col][k]  (zi half s=0, zj half s=1)
        s16x8 gA0 = *(const s16x8*)(z_loop + (size_t)srcA * 32 + quad * 8);
        s16x8 gA1 = *(const s16x8*)(z_loop + (size_t)dstA * 32 + quad * 8);
        s16x8 gB0 = *(const s16x8*)(z_loop + (size_t)srcB * 32 + quad * 8);
        s16x8 gB1 = *(const s16x8*)(z_loop + (size_t)dstB * 32 + quad * 8);

        // he^T[m=hidden][n=edge]: 4 M-tiles x 2 K-steps per 16 edges
        f32x4v accA[4], accB[4];
        for (int mt = 0; mt < 4; ++mt) {
            f32x4v c = {bias1[mt][0], bias1[mt][1], bias1[mt][2], bias1[mt][3]};
            c = __builtin_amdgcn_mfma_f32_16x16x32_bf16(aw[0][mt], gA0, c, 0, 0, 0);
            c = __builtin_amdgcn_mfma_f32_16x16x32_bf16(aw[1][mt], gA1, c, 0, 0, 0);
            accA[mt] = c;
        }
        for (int mt = 0; mt < 4; ++mt) {
            f32x4v c = {bias1[mt][0], bias1[mt][1], bias1[mt][2], bias1[mt][3]};
            c = __builtin_amdgcn_mfma_f32_16x16x32_bf16(aw[0][mt], gB0, c, 0, 0, 0);
            c = __builtin_amdgcn_mfma_f32_16x16x32_bf16(aw[1][mt], gB1, c, 0, 0, 0);
            accB[mt] = c;
        }

        // relu + dw2-dot: each lane owns 16 hidden units of ONE edge (n=col),
        // hidden h = 16mt + quad*4 + r. In-lane fma, then 2-step quad reduce.
        float pA = 0.f, pB = 0.f;
        for (int mt = 0; mt < 4; ++mt)
            for (int r = 0; r < 4; ++r) {
                float vA = accA[mt][r]; vA = vA > 0.f ? vA : 0.f;
                float vB = accB[mt][r]; vB = vB > 0.f ? vB : 0.f;
                pA += vA * w2v[mt][r];
                pB += vB * w2v[mt][r];
            }
        pA += __shfl_xor(pA, 16, 64);
        pA += __shfl_xor(pA, 32, 64);
        pB += __shfl_xor(pB, 16, 64);
        pB += __shfl_xor(pB, 32, 64);

        // lanes 0-15: edge e0+lane (tile A); lanes 16-31: e0+lane (tile B,
        // since col = lane-16 -> edge e0+16+col = e0+lane). One 128B store.
        if (lane < 32) {
            float v = (lane < 16 ? pA : pB) + bias2;
            out[e0 + lane] = v;
        }
    }
}

extern "C" void kernel_launch(void* const* d_in, const int* in_sizes, int n_in,
                              void* d_out, int out_size, void* d_ws, size_t ws_size,
                              hipStream_t stream) {
    const float* z_mod = (const float*)d_in[0];
    const int*   eidx  = (const int*)d_in[1];
    const float* w1    = (const float*)d_in[2];
    const float* b1    = (const float*)d_in[3];
    const float* w2    = (const float*)d_in[4];
    const float* b2    = (const float*)d_in[5];
    const float* dw1   = (const float*)d_in[6];
    const float* db1   = (const float*)d_in[7];
    const float* dw2   = (const float*)d_in[8];
    const float* db2   = (const float*)d_in[9];
    float*          out    = (float*)d_out;
    unsigned short* z_loop = (unsigned short*)d_ws;   // 100000*32*2B = 6.4 MB

    node_proj_kernel<<<512, 256, 0, stream>>>(z_mod, w1, b1, w2, b2, z_loop);
    edge_dec_kernel<<<1536, 256, 0, stream>>>(eidx, z_loop, dw1, db1, dw2, db2, out);
}

// Round 9
// 151.240 us; speedup vs baseline: 1.3266x; 1.0649x over previous
//
#include <hip/hip_runtime.h>

// LoopHead: node MLP (32->64->32) then edge decoder (gather/concat -> 64 -> 1)
// Wire dtypes per the reference: fp32 tensors, int32 edge_index, fp32 out.
// R9 = R7 (proven) + register prefetch of NEXT iteration's 4 edge indices.
// Empirical rule from R5/R8 failures: keep edge kernel low-pressure (no big
// unrolls, no gather-frag rotation) — only 4 scalar ints rotate here.

typedef short bfrag4 __attribute__((ext_vector_type(4)));  // 4 bf16 (x16 frag)
typedef short s16x8  __attribute__((ext_vector_type(8)));  // 8 bf16 (x32 frag)
typedef float f32x4v __attribute__((ext_vector_type(4)));  // fp32 x4

#define N_NODES 100000
#define N_EDGES 3200000

__device__ __forceinline__ unsigned short f2bf(float f) {
    unsigned int i = __float_as_uint(f);
    unsigned int r = i + 0x7FFFu + ((i >> 16) & 1u);  // RNE
    return (unsigned short)(r >> 16);
}

__device__ __forceinline__ bfrag4 cvt4(float x0, float x1, float x2, float x3) {
    bfrag4 v;
    v[0] = (short)f2bf(x0);
    v[1] = (short)f2bf(x1);
    v[2] = (short)f2bf(x2);
    v[3] = (short)f2bf(x3);
    return v;
}

// ---------------- Kernel 1: node projection -> z_loop (bf16 [N,32]) --------
// (verbatim round-3/6/7 version — proven through all harness checks)
__global__ __launch_bounds__(256) void node_proj_kernel(
    const float* __restrict__ z_mod,   // [N,32] fp32
    const float* __restrict__ w1,      // [32,64] row-major (k,n)
    const float* __restrict__ b1,      // [64]
    const float* __restrict__ w2,      // [64,32] row-major (k,n)
    const float* __restrict__ b2,      // [32]
    unsigned short* __restrict__ z_loop)  // [N,32] bf16 out (workspace)
{
    __shared__ unsigned short hbuf[4][16 * 72];

    const int tid  = threadIdx.x;
    const int wave = tid >> 6;
    const int lane = tid & 63;
    const int quad = lane >> 4;
    const int col  = lane & 15;

    bfrag4 bw1[2][4];   // stage 1: K=32 (2 steps), N=64 (4 n-tiles)
    float  bias1[4];
    for (int t = 0; t < 4; ++t) {
        const int n = col + 16 * t;
        for (int s = 0; s < 2; ++s)
            for (int j = 0; j < 4; ++j)
                bw1[s][t][j] = (short)f2bf(w1[(s * 16 + quad * 4 + j) * 64 + n]);
        bias1[t] = b1[n];
    }
    bfrag4 bw2[4][2];   // stage 2: K=64 (4 steps), N=32 (2 n-tiles)
    float  bias2[2];
    for (int t = 0; t < 2; ++t) {
        const int n = col + 16 * t;
        for (int s = 0; s < 4; ++s)
            for (int j = 0; j < 4; ++j)
                bw2[s][t][j] = (short)f2bf(w2[(s * 16 + quad * 4 + j) * 32 + n]);
        bias2[t] = b2[n];
    }

    unsigned short* hrow = &hbuf[wave][0];

    const int gwave  = blockIdx.x * 4 + wave;
    const int nwaves = gridDim.x * 4;
    const int ntiles = N_NODES / 16;   // 6250, exact

    for (int tile = gwave; tile < ntiles; tile += nwaves) {
        const int node0 = tile * 16;
        const float* zrow = z_mod + (size_t)(node0 + col) * 32;

        f32x4v za0 = *(const f32x4v*)(zrow + 0 * 16 + quad * 4);
        f32x4v za1 = *(const f32x4v*)(zrow + 1 * 16 + quad * 4);
        bfrag4 a10 = cvt4(za0[0], za0[1], za0[2], za0[3]);
        bfrag4 a11 = cvt4(za1[0], za1[1], za1[2], za1[3]);

        f32x4v acc[4];
        for (int t = 0; t < 4; ++t) {
            f32x4v c = {bias1[t], bias1[t], bias1[t], bias1[t]};
            c = __builtin_amdgcn_mfma_f32_16x16x16bf16_1k(a10, bw1[0][t], c, 0, 0, 0);
            c = __builtin_amdgcn_mfma_f32_16x16x16bf16_1k(a11, bw1[1][t], c, 0, 0, 0);
            acc[t] = c;
        }

        for (int t = 0; t < 4; ++t)
            for (int r = 0; r < 4; ++r) {
                float v = acc[t][r];
                v = v > 0.f ? v : 0.f;
                hrow[(quad * 4 + r) * 72 + (col + 16 * t)] = f2bf(v);
            }
        asm volatile("" ::: "memory");

        f32x4v acc2[2];
        for (int t = 0; t < 2; ++t)
            acc2[t] = (f32x4v){bias2[t], bias2[t], bias2[t], bias2[t]};
        for (int s = 0; s < 4; ++s) {
            bfrag4 a2 = *(const bfrag4*)(hrow + col * 72 + s * 16 + quad * 4);
            for (int t = 0; t < 2; ++t)
                acc2[t] = __builtin_amdgcn_mfma_f32_16x16x16bf16_1k(a2, bw2[s][t], acc2[t], 0, 0, 0);
        }
        asm volatile("" ::: "memory");

        for (int t = 0; t < 2; ++t)
            for (int r = 0; r < 4; ++r)
                z_loop[(size_t)(node0 + quad * 4 + r) * 32 + (col + 16 * t)] =
                    f2bf(acc2[t][r]);
    }
}

// ---------------- Kernel 2: edge decoder (R7 + index prefetch) --------------
__global__ __launch_bounds__(256) void edge_dec_kernel(
    const int*            __restrict__ eidx,     // [2, E] int32
    const unsigned short* __restrict__ z_loop,   // [N,32] bf16
    const float*          __restrict__ dw1,      // [64,64] row-major (k,n)
    const float*          __restrict__ db1,      // [64]
    const float*          __restrict__ dw2,      // [64]
    const float*          __restrict__ db2,      // [1]
    float* __restrict__ out)                     // [E] fp32
{
    const int tid  = threadIdx.x;
    const int lane = tid & 63;
    const int quad = lane >> 4;
    const int col  = lane & 15;

    // A-frags = dw1^T tiles: aw[s][mt] holds A[m=16mt+col][k=32s+quad*8+j]
    s16x8 aw[2][4];
    float bias1[4][4];   // [mt][r] = db1[16mt + quad*4 + r]
    float w2v[4][4];     // [mt][r] = dw2[16mt + quad*4 + r]
    for (int mt = 0; mt < 4; ++mt) {
        const int h = 16 * mt + col;
        for (int s = 0; s < 2; ++s)
            for (int j = 0; j < 8; ++j)
                aw[s][mt][j] = (short)f2bf(dw1[(32 * s + quad * 8 + j) * 64 + h]);
        for (int r = 0; r < 4; ++r) {
            bias1[mt][r] = db1[16 * mt + quad * 4 + r];
            w2v[mt][r]   = dw2[16 * mt + quad * 4 + r];
        }
    }
    const float bias2 = db2[0];

    const int gwave  = blockIdx.x * 4 + (tid >> 6);
    const int nwaves = gridDim.x * 4;
    const int npairs = N_EDGES / 32;   // 100000, exact (2 tiles of 16 per iter)

    // prefetch indices for the first iteration (gwave < npairs always:
    // nwaves = 6144 <= npairs)
    int sA = eidx[gwave * 32 + col];
    int sB = eidx[gwave * 32 + 16 + col];
    int dA = eidx[N_EDGES + gwave * 32 + col];
    int dB = eidx[N_EDGES + gwave * 32 + 16 + col];

    for (int p = gwave; p < npairs; p += nwaves) {
        const int e0 = p * 32;

        // 4 independent 16B gathers — each IS a B-fragment
        // (B[k=quad*8+j][n=col]); issued first, consumed after the prefetch.
        s16x8 gA0 = *(const s16x8*)(z_loop + (size_t)sA * 32 + quad * 8);
        s16x8 gA1 = *(const s16x8*)(z_loop + (size_t)dA * 32 + quad * 8);
        s16x8 gB0 = *(const s16x8*)(z_loop + (size_t)sB * 32 + quad * 8);
        s16x8 gB1 = *(const s16x8*)(z_loop + (size_t)dB * 32 + quad * 8);

        // prefetch NEXT iteration's indices (branchless clamp to own first
        // tile — always valid, result unused on the last iteration)
        const int pn = p + nwaves;
        const int pc = pn < npairs ? pn : gwave;
        sA = eidx[pc * 32 + col];
        sB = eidx[pc * 32 + 16 + col];
        dA = eidx[N_EDGES + pc * 32 + col];
        dB = eidx[N_EDGES + pc * 32 + 16 + col];

        // he^T[m=hidden][n=edge]: 4 M-tiles x 2 K-steps per 16 edges
        f32x4v accA[4], accB[4];
        for (int mt = 0; mt < 4; ++mt) {
            f32x4v c = {bias1[mt][0], bias1[mt][1], bias1[mt][2], bias1[mt][3]};
            c = __builtin_amdgcn_mfma_f32_16x16x32_bf16(aw[0][mt], gA0, c, 0, 0, 0);
            c = __builtin_amdgcn_mfma_f32_16x16x32_bf16(aw[1][mt], gA1, c, 0, 0, 0);
            accA[mt] = c;
        }
        for (int mt = 0; mt < 4; ++mt) {
            f32x4v c = {bias1[mt][0], bias1[mt][1], bias1[mt][2], bias1[mt][3]};
            c = __builtin_amdgcn_mfma_f32_16x16x32_bf16(aw[0][mt], gB0, c, 0, 0, 0);
            c = __builtin_amdgcn_mfma_f32_16x16x32_bf16(aw[1][mt], gB1, c, 0, 0, 0);
            accB[mt] = c;
        }

        // relu + dw2-dot: lane owns 16 hidden units of ONE edge (n=col);
        // in-lane fma then 2-step quad reduce.
        float pA = 0.f, pB = 0.f;
        for (int mt = 0; mt < 4; ++mt)
            for (int r = 0; r < 4; ++r) {
                float vA = accA[mt][r]; vA = vA > 0.f ? vA : 0.f;
                float vB = accB[mt][r]; vB = vB > 0.f ? vB : 0.f;
                pA += vA * w2v[mt][r];
                pB += vB * w2v[mt][r];
            }
        pA += __shfl_xor(pA, 16, 64);
        pA += __shfl_xor(pA, 32, 64);
        pB += __shfl_xor(pB, 16, 64);
        pB += __shfl_xor(pB, 32, 64);

        // lanes 0-15: edge e0+lane (tile A); 16-31: e0+lane (tile B).
        if (lane < 32) {
            float v = (lane < 16 ? pA : pB) + bias2;
            out[e0 + lane] = v;
        }
    }
}

extern "C" void kernel_launch(void* const* d_in, const int* in_sizes, int n_in,
                              void* d_out, int out_size, void* d_ws, size_t ws_size,
                              hipStream_t stream) {
    const float* z_mod = (const float*)d_in[0];
    const int*   eidx  = (const int*)d_in[1];
    const float* w1    = (const float*)d_in[2];
    const float* b1    = (const float*)d_in[3];
    const float* w2    = (const float*)d_in[4];
    const float* b2    = (const float*)d_in[5];
    const float* dw1   = (const float*)d_in[6];
    const float* db1   = (const float*)d_in[7];
    const float* dw2   = (const float*)d_in[8];
    const float* db2   = (const float*)d_in[9];
    float*          out    = (float*)d_out;
    unsigned short* z_loop = (unsigned short*)d_ws;   // 100000*32*2B = 6.4 MB

    node_proj_kernel<<<512, 256, 0, stream>>>(z_mod, w1, b1, w2, b2, z_loop);
    edge_dec_kernel<<<1536, 256, 0, stream>>>(eidx, z_loop, dw1, db1, dw2, db2, out);
}